// Round 4
// baseline (747.500 us; speedup 1.0000x reference)
//
#include <hip/hip_runtime.h>
#include <hip/hip_bf16.h>

typedef __attribute__((ext_vector_type(4))) float  floatx4;
typedef __attribute__((ext_vector_type(8))) short  shortx8;
typedef __attribute__((ext_vector_type(4))) short  shortx4;

// ---------- bf16 helpers (bit-level, RNE) ----------
__device__ __forceinline__ short f2bf(float f) {
    unsigned u = __float_as_uint(f);
    u += 0x7fffu + ((u >> 16) & 1u);
    return (short)(u >> 16);
}
__device__ __forceinline__ float bf2f(short s) {
    return __uint_as_float(((unsigned)(unsigned short)s) << 16);
}
__device__ __forceinline__ float fast_exp2(float x) {
#if __has_builtin(__builtin_amdgcn_exp2f)
    return __builtin_amdgcn_exp2f(x);
#else
    return exp2f(x);
#endif
}

// ---------- async global->LDS, 16B per lane ----------
__device__ __forceinline__ void load_lds16(const void* g, void* l) {
    __builtin_amdgcn_global_load_lds(
        (const __attribute__((address_space(1))) unsigned int*)g,
        (__attribute__((address_space(3))) unsigned int*)l,
        16, 0, 0);
}

// =====================================================================
// Weight transpose+convert: src fp32 [K][N] -> dst bf16 [N][K]
// =====================================================================
__global__ __launch_bounds__(256)
void transpose_w(const float* __restrict__ src, short* __restrict__ dst, int K, int N)
{
    __shared__ __align__(16) float tile[32][33];
    const int n0 = blockIdx.x * 32, k0 = blockIdx.y * 32;
    const int tx = threadIdx.x & 31, ty = threadIdx.x >> 5;   // ty 0..7
    for (int i = 0; i < 32; i += 8)
        tile[ty + i][tx] = src[(size_t)(k0 + ty + i) * N + n0 + tx];
    __syncthreads();
    for (int i = 0; i < 32; i += 8)
        dst[(size_t)(n0 + ty + i) * K + k0 + tx] = f2bf(tile[tx][ty + i]);
}

// =====================================================================
// LayerNorm fp32 [8192][1024] -> bf16, 1 block/row
// =====================================================================
__global__ __launch_bounds__(256)
void ln_bf16(const float* __restrict__ x, const float* __restrict__ g,
             const float* __restrict__ be, short* __restrict__ out)
{
    const int row = blockIdx.x;
    const int tid = threadIdx.x;
    const float4 v = reinterpret_cast<const float4*>(x + (size_t)row * 1024)[tid];
    float s  = v.x + v.y + v.z + v.w;
    float ss = v.x * v.x + v.y * v.y + v.z * v.z + v.w * v.w;
    for (int off = 32; off > 0; off >>= 1) {
        s  += __shfl_down(s,  off);
        ss += __shfl_down(ss, off);
    }
    __shared__ float rs[4], rss[4];
    const int wave = tid >> 6, lane = tid & 63;
    if (lane == 0) { rs[wave] = s; rss[wave] = ss; }
    __syncthreads();
    const float S    = rs[0] + rs[1] + rs[2] + rs[3];
    const float SS   = rss[0] + rss[1] + rss[2] + rss[3];
    const float mean = S * (1.0f / 1024.0f);
    const float var  = SS * (1.0f / 1024.0f) - mean * mean;
    const float rstd = rsqrtf(var + 1e-5f);
    const float4 gg = reinterpret_cast<const float4*>(g)[tid];
    const float4 bb = reinterpret_cast<const float4*>(be)[tid];
    shortx4 o;
    o[0] = f2bf(gg.x * ((v.x - mean) * rstd) + bb.x);
    o[1] = f2bf(gg.y * ((v.y - mean) * rstd) + bb.y);
    o[2] = f2bf(gg.z * ((v.z - mean) * rstd) + bb.z);
    o[3] = f2bf(gg.w * ((v.w - mean) * rstd) + bb.w);
    *reinterpret_cast<shortx4*>(out + (size_t)row * 1024 + tid * 4) = o;
}

// =====================================================================
// m97-style bf16 GEMM: C[M][N] = A[M][K] @ Bt[N][K]^T, fused epilogues.
// EPI 0: store bf16
// EPI 1: +bias, relu, store bf16
// EPI 2: fp32 out = resid + acc
// EPI 3: fp32 out = resid + acc + bias
// =====================================================================
template <int EPI>
__global__ __launch_bounds__(256)
void gemm_bt(const short* __restrict__ A, const short* __restrict__ Bt,
             short* __restrict__ Cb, float* __restrict__ Cf,
             const float* __restrict__ bias, const float* __restrict__ resid,
             int M, int N, int K)
{
    __shared__ __align__(16) short As[128 * 32];
    __shared__ __align__(16) short Bs[128 * 32];
    const int tid  = threadIdx.x;
    const int wave = tid >> 6;
    const int lane = tid & 63;
    const int quad = lane >> 4;
    const int l16  = lane & 15;
    const int wm = wave >> 1, wn = wave & 1;          // 2x2 waves, 64x64 each
    const size_t bm = (size_t)blockIdx.y * 128;
    const size_t bn = (size_t)blockIdx.x * 128;

    floatx4 acc[4][4];
    for (int i = 0; i < 4; i++)
        for (int j = 0; j < 4; j++)
            acc[i][j] = (floatx4){0.f, 0.f, 0.f, 0.f};

    const int c0 = wave * 2, c1 = wave * 2 + 1;
    const int rA0 = c0 * 16 + (lane >> 2);
    const int rA1 = c1 * 16 + (lane >> 2);
    const int colOff = (lane & 3) * 8;

    for (int k0 = 0; k0 < K; k0 += 32) {
        load_lds16(A  + (bm + rA0) * (size_t)K + k0 + colOff, &As[c0 * 512]);
        load_lds16(A  + (bm + rA1) * (size_t)K + k0 + colOff, &As[c1 * 512]);
        load_lds16(Bt + (bn + rA0) * (size_t)K + k0 + colOff, &Bs[c0 * 512]);
        load_lds16(Bt + (bn + rA1) * (size_t)K + k0 + colOff, &Bs[c1 * 512]);
        __syncthreads();
        shortx8 af[4], bf[4];
        for (int mi = 0; mi < 4; mi++)
            af[mi] = *(const shortx8*)&As[(wm * 64 + mi * 16 + l16) * 32 + quad * 8];
        for (int ni = 0; ni < 4; ni++)
            bf[ni] = *(const shortx8*)&Bs[(wn * 64 + ni * 16 + l16) * 32 + quad * 8];
        for (int mi = 0; mi < 4; mi++)
            for (int ni = 0; ni < 4; ni++)
                acc[mi][ni] = __builtin_amdgcn_mfma_f32_16x16x32_bf16(
                    af[mi], bf[ni], acc[mi][ni], 0, 0, 0);
        __syncthreads();
    }

    for (int mi = 0; mi < 4; mi++) {
        for (int ni = 0; ni < 4; ni++) {
            const size_t row0 = bm + wm * 64 + mi * 16 + quad * 4;
            const size_t col  = bn + wn * 64 + ni * 16 + l16;
            for (int r = 0; r < 4; r++) {
                float v = acc[mi][ni][r];
                const size_t idx = (row0 + r) * (size_t)N + col;
                if (EPI == 0) {
                    Cb[idx] = f2bf(v);
                } else if (EPI == 1) {
                    v += bias[col];
                    Cb[idx] = f2bf(v > 0.f ? v : 0.f);
                } else if (EPI == 2) {
                    Cf[idx] = resid[idx] + v;
                } else {
                    v += bias[col];
                    Cf[idx] = resid[idx] + v;
                }
            }
        }
    }
}

// =====================================================================
// V transpose: qkv v-part -> vt[b][h][64 d][2048 s] bf16
// =====================================================================
__global__ __launch_bounds__(256)
void transpose_v(const short* __restrict__ qkv, short* __restrict__ vt)
{
    __shared__ __align__(16) short tile[64][65];
    const int st = blockIdx.x, h = blockIdx.y, b = blockIdx.z;
    const int t = threadIdx.x;
    for (int i = 0; i < 2; i++) {
        const int idx = i * 256 + t;
        const int s = idx >> 3, dg = idx & 7;
        shortx8 val = *(const shortx8*)&qkv[(size_t)(b * 2048 + st * 64 + s) * 3072
                                           + 2048 + h * 64 + dg * 8];
        for (int u = 0; u < 8; u++) tile[s][dg * 8 + u] = val[u];
    }
    __syncthreads();
    const int d = t >> 2, sg = (t & 3) * 16;
    shortx8 lo, hi;
    for (int i = 0; i < 8; i++) {
        lo[i] = tile[sg + i][d];
        hi[i] = tile[sg + 8 + i][d];
    }
    const size_t base = ((size_t)(b * 16 + h) * 64 + d) * 2048 + st * 64 + sg;
    *(shortx8*)&vt[base]     = lo;
    *(shortx8*)&vt[base + 8] = hi;
}

// =====================================================================
// Flash attention v4: barrier-free. 1 WG per (qt of 128 rows, h, b);
// each of 4 waves independently owns 32 q-rows and iterates all K-tiles.
//  - K and V fragments loaded DIRECTLY from global (L2-resident);
//    no K/V LDS staging, no __syncthreads anywhere.
//  - no running max; S^T = K.Q^T; l via constant-ones B-operand MFMA.
//  - only LDS use: wave-private P^T transpose (lgkmcnt drain only).
// qkv: [8192][3072] bf16 (q|k|v). vt: [b][h][64][2048] bf16. ctx: [8192][1024] bf16.
// =====================================================================
__global__ __launch_bounds__(256)
void attention_kernel(const short* __restrict__ qkv, const short* __restrict__ vt,
                      short* __restrict__ ctx)
{
    const int qt = blockIdx.x, h = blockIdx.y, b = blockIdx.z;
    const int tid  = threadIdx.x;
    const int wave = tid >> 6;
    const int lane = tid & 63;
    const int quad = lane >> 4;
    const int l16  = lane & 15;

    __shared__ __align__(16) short Ps[4][32 * 72];    // per-wave P^T [q_local][k]

    // Q fragments: B-operand, q-row = l16; pre-scaled by (1/8)*log2(e)
    const int q0 = qt * 128 + wave * 32;
    const float qscale = 0.125f * 1.44269504088896f;
    shortx8 qf[2][2];
    for (int qi = 0; qi < 2; qi++) {
        const short* qrow = qkv + (size_t)(b * 2048 + q0 + qi * 16 + l16) * 3072 + h * 64;
        for (int kk = 0; kk < 2; kk++) {
            shortx8 raw = *(const shortx8*)&qrow[kk * 32 + quad * 8];
            for (int j = 0; j < 8; j++) raw[j] = f2bf(bf2f(raw[j]) * qscale);
            qf[qi][kk] = raw;
        }
    }

    // constant-ones B-operand fragment for the l row-sum MFMA
    shortx8 vones;
    for (int j = 0; j < 8; j++) vones[j] = (short)0x3F80;

    floatx4 accO[2][5];   // [qi][dt]; dt 0..3 = O columns; dt 4 = row-sum l
    for (int qi = 0; qi < 2; qi++)
        for (int dt = 0; dt < 5; dt++) accO[qi][dt] = (floatx4){0.f, 0.f, 0.f, 0.f};

    const short* kbase = qkv + (size_t)(b * 2048) * 3072 + 1024 + h * 64;
    const short* vbase = vt + ((size_t)(b * 16 + h) * 64) * 2048;
    short* const psw = &Ps[wave][0];

    for (int kt = 0; kt < 32; ++kt) {
        // S^T = K.Q^T : K fragments straight from global (B[n=k_seq][k=d])
        floatx4 st[4][2];
        for (int nt = 0; nt < 4; nt++) {
            const short* kp = kbase + (size_t)(kt * 64 + nt * 16 + l16) * 3072 + quad * 8;
            shortx8 kf0 = *(const shortx8*)kp;
            shortx8 kf1 = *(const shortx8*)(kp + 32);
            for (int qi = 0; qi < 2; qi++) {
                floatx4 c = (floatx4){0.f, 0.f, 0.f, 0.f};
                c = __builtin_amdgcn_mfma_f32_16x16x32_bf16(kf0, qf[qi][0], c, 0, 0, 0);
                c = __builtin_amdgcn_mfma_f32_16x16x32_bf16(kf1, qf[qi][1], c, 0, 0, 0);
                st[nt][qi] = c;
            }
        }

        // p = 2^s, pack 4 bf16, store P^T[q_local][k] (wave-private LDS)
        for (int nt = 0; nt < 4; nt++)
            for (int qi = 0; qi < 2; qi++) {
                float2 p01, p23;
                p01.x = fast_exp2(st[nt][qi][0]);
                p01.y = fast_exp2(st[nt][qi][1]);
                p23.x = fast_exp2(st[nt][qi][2]);
                p23.y = fast_exp2(st[nt][qi][3]);
                union { __hip_bfloat162 h2[2]; uint2 u; } pk;
                pk.h2[0] = __float22bfloat162_rn(p01);
                pk.h2[1] = __float22bfloat162_rn(p23);
                *(uint2*)&psw[(qi * 16 + l16) * 72 + nt * 16 + quad * 4] = pk.u;
            }
        asm volatile("s_waitcnt lgkmcnt(0)" ::: "memory");

        shortx8 pf[2][2];
        for (int qi = 0; qi < 2; qi++)
            for (int kk = 0; kk < 2; kk++)
                pf[qi][kk] = *(const shortx8*)&psw[(qi * 16 + l16) * 72 + kk * 32 + quad * 8];

        // O[q][d] += P.V : V fragments straight from global (B[n=d][k=s])
        for (int dt = 0; dt < 4; dt++) {
            const short* vp = vbase + (size_t)(dt * 16 + l16) * 2048 + kt * 64 + quad * 8;
            shortx8 vf0 = *(const shortx8*)vp;
            shortx8 vf1 = *(const shortx8*)(vp + 32);
            for (int qi = 0; qi < 2; qi++) {
                floatx4 c = accO[qi][dt];
                c = __builtin_amdgcn_mfma_f32_16x16x32_bf16(pf[qi][0], vf0, c, 0, 0, 0);
                c = __builtin_amdgcn_mfma_f32_16x16x32_bf16(pf[qi][1], vf1, c, 0, 0, 0);
                accO[qi][dt] = c;
            }
        }
        // l = sum_k P via constant ones
        for (int qi = 0; qi < 2; qi++) {
            floatx4 c = accO[qi][4];
            c = __builtin_amdgcn_mfma_f32_16x16x32_bf16(pf[qi][0], vones, c, 0, 0, 0);
            c = __builtin_amdgcn_mfma_f32_16x16x32_bf16(pf[qi][1], vones, c, 0, 0, 0);
            accO[qi][4] = c;
        }
    }

    // epilogue: ctx = O / l   (l identical across l16 in accO[qi][4])
    for (int qi = 0; qi < 2; qi++) {
        const int qg = q0 + qi * 16 + quad * 4;
        for (int r = 0; r < 4; r++) {
            const float inv = 1.0f / accO[qi][4][r];
            for (int dt = 0; dt < 4; dt++)
                ctx[(size_t)(b * 2048 + qg + r) * 1024 + h * 64 + dt * 16 + l16]
                    = f2bf(accO[qi][dt][r] * inv);
        }
    }
}

// =====================================================================
// launch
// =====================================================================
extern "C" void kernel_launch(void* const* d_in, const int* in_sizes, int n_in,
                              void* d_out, int out_size, void* d_ws, size_t ws_size,
                              hipStream_t stream)
{
    const float* x   = (const float*)d_in[0];
    const float* Wq  = (const float*)d_in[1];
    const float* Wk  = (const float*)d_in[2];
    const float* Wv  = (const float*)d_in[3];
    const float* Wo  = (const float*)d_in[4];
    const float* W1  = (const float*)d_in[5];
    const float* b1  = (const float*)d_in[6];
    const float* W2  = (const float*)d_in[7];
    const float* b2  = (const float*)d_in[8];
    const float* g1  = (const float*)d_in[9];
    const float* be1 = (const float*)d_in[10];
    const float* g2  = (const float*)d_in[11];
    const float* be2 = (const float*)d_in[12];
    float* out = (float*)d_out;
    char*  ws  = (char*)d_ws;

    const size_t MiB = 1u << 20;
    short* regA   = (short*)(ws);                 // 16 MiB: ln1 -> ctx -> ln2
    short* qkv    = (short*)(ws + 16 * MiB);      // 48 MiB
    short* vt     = (short*)(ws + 64 * MiB);      // 16 MiB
    short* ff1    = qkv;                          // 64 MiB alias (qkv+vt dead)
    short* Wqkv_t = (short*)(ws + 80 * MiB);      // 6 MiB
    short* Wo_t   = (short*)(ws + 86 * MiB);      // 2 MiB
    short* W1_t   = (short*)(ws + 88 * MiB);      // 8 MiB
    short* W2_t   = (short*)(ws + 96 * MiB);      // 8 MiB  (total 104 MiB)

    const dim3 blk(256);

    // weights -> bf16 BT layout
    transpose_w<<<dim3(32, 32),  blk, 0, stream>>>(Wq, Wqkv_t,                  1024, 1024);
    transpose_w<<<dim3(32, 32),  blk, 0, stream>>>(Wk, Wqkv_t + 1024 * 1024,    1024, 1024);
    transpose_w<<<dim3(32, 32),  blk, 0, stream>>>(Wv, Wqkv_t + 2 * 1024 * 1024,1024, 1024);
    transpose_w<<<dim3(32, 32),  blk, 0, stream>>>(Wo, Wo_t,                    1024, 1024);
    transpose_w<<<dim3(128, 32), blk, 0, stream>>>(W1, W1_t,                    1024, 4096);
    transpose_w<<<dim3(32, 128), blk, 0, stream>>>(W2, W2_t,                    4096, 1024);

    // LN1
    ln_bf16<<<8192, blk, 0, stream>>>(x, g1, be1, regA);
    // QKV
    gemm_bt<0><<<dim3(24, 64), blk, 0, stream>>>(regA, Wqkv_t, qkv, nullptr, nullptr, nullptr,
                                                 8192, 3072, 1024);
    // V^T
    transpose_v<<<dim3(32, 16, 4), blk, 0, stream>>>(qkv, vt);
    // attention -> ctx (regA)
    attention_kernel<<<dim3(16, 16, 4), blk, 0, stream>>>(qkv, vt, regA);
    // attn_out @ Wo + x -> out (fp32)
    gemm_bt<2><<<dim3(8, 64), blk, 0, stream>>>(regA, Wo_t, nullptr, out, nullptr, x,
                                                8192, 1024, 1024);
    // LN2 -> regA
    ln_bf16<<<8192, blk, 0, stream>>>(out, g2, be2, regA);
    // FF1: relu(ln2 @ W1 + b1) -> ff1 (bf16)
    gemm_bt<1><<<dim3(32, 64), blk, 0, stream>>>(regA, W1_t, ff1, nullptr, b1, nullptr,
                                                 8192, 4096, 1024);
    // FF2: out += ff1 @ W2 + b2
    gemm_bt<3><<<dim3(8, 64), blk, 0, stream>>>(ff1, W2_t, nullptr, out, b2, out,
                                                8192, 1024, 4096);
}

// Round 5
// 585.755 us; speedup vs baseline: 1.2761x; 1.2761x over previous
//
#include <hip/hip_runtime.h>
#include <hip/hip_bf16.h>

typedef __attribute__((ext_vector_type(4))) float  floatx4;
typedef __attribute__((ext_vector_type(8))) short  shortx8;
typedef __attribute__((ext_vector_type(4))) short  shortx4;

// ---------- bf16 helpers (bit-level, RNE) ----------
__device__ __forceinline__ short f2bf(float f) {
    unsigned u = __float_as_uint(f);
    u += 0x7fffu + ((u >> 16) & 1u);
    return (short)(u >> 16);
}
__device__ __forceinline__ float bf2f(short s) {
    return __uint_as_float(((unsigned)(unsigned short)s) << 16);
}
__device__ __forceinline__ float fast_exp2(float x) {
#if __has_builtin(__builtin_amdgcn_exp2f)
    return __builtin_amdgcn_exp2f(x);
#else
    return exp2f(x);
#endif
}

// ---------- async global->LDS, 16B per lane ----------
__device__ __forceinline__ void load_lds16(const void* g, void* l) {
    __builtin_amdgcn_global_load_lds(
        (const __attribute__((address_space(1))) unsigned int*)g,
        (__attribute__((address_space(3))) unsigned int*)l,
        16, 0, 0);
}

// =====================================================================
// Weight transpose+convert: src fp32 [K][N] -> dst bf16 [N][K]
// =====================================================================
__global__ __launch_bounds__(256)
void transpose_w(const float* __restrict__ src, short* __restrict__ dst, int K, int N)
{
    __shared__ __align__(16) float tile[32][33];
    const int n0 = blockIdx.x * 32, k0 = blockIdx.y * 32;
    const int tx = threadIdx.x & 31, ty = threadIdx.x >> 5;   // ty 0..7
    for (int i = 0; i < 32; i += 8)
        tile[ty + i][tx] = src[(size_t)(k0 + ty + i) * N + n0 + tx];
    __syncthreads();
    for (int i = 0; i < 32; i += 8)
        dst[(size_t)(n0 + ty + i) * K + k0 + tx] = f2bf(tile[tx][ty + i]);
}

// =====================================================================
// LayerNorm fp32 [8192][1024] -> bf16, 1 block/row
// =====================================================================
__global__ __launch_bounds__(256)
void ln_bf16(const float* __restrict__ x, const float* __restrict__ g,
             const float* __restrict__ be, short* __restrict__ out)
{
    const int row = blockIdx.x;
    const int tid = threadIdx.x;
    const float4 v = reinterpret_cast<const float4*>(x + (size_t)row * 1024)[tid];
    float s  = v.x + v.y + v.z + v.w;
    float ss = v.x * v.x + v.y * v.y + v.z * v.z + v.w * v.w;
    for (int off = 32; off > 0; off >>= 1) {
        s  += __shfl_down(s,  off);
        ss += __shfl_down(ss, off);
    }
    __shared__ float rs[4], rss[4];
    const int wave = tid >> 6, lane = tid & 63;
    if (lane == 0) { rs[wave] = s; rss[wave] = ss; }
    __syncthreads();
    const float S    = rs[0] + rs[1] + rs[2] + rs[3];
    const float SS   = rss[0] + rss[1] + rss[2] + rss[3];
    const float mean = S * (1.0f / 1024.0f);
    const float var  = SS * (1.0f / 1024.0f) - mean * mean;
    const float rstd = rsqrtf(var + 1e-5f);
    const float4 gg = reinterpret_cast<const float4*>(g)[tid];
    const float4 bb = reinterpret_cast<const float4*>(be)[tid];
    shortx4 o;
    o[0] = f2bf(gg.x * ((v.x - mean) * rstd) + bb.x);
    o[1] = f2bf(gg.y * ((v.y - mean) * rstd) + bb.y);
    o[2] = f2bf(gg.z * ((v.z - mean) * rstd) + bb.z);
    o[3] = f2bf(gg.w * ((v.w - mean) * rstd) + bb.w);
    *reinterpret_cast<shortx4*>(out + (size_t)row * 1024 + tid * 4) = o;
}

// =====================================================================
// m97-style bf16 GEMM: C[M][N] = A[M][K] @ Bt[N][K]^T, fused epilogues.
// EPI 0: store bf16
// EPI 1: +bias, relu, store bf16
// EPI 2: fp32 out = resid + acc
// EPI 3: fp32 out = resid + acc + bias
// =====================================================================
template <int EPI>
__global__ __launch_bounds__(256)
void gemm_bt(const short* __restrict__ A, const short* __restrict__ Bt,
             short* __restrict__ Cb, float* __restrict__ Cf,
             const float* __restrict__ bias, const float* __restrict__ resid,
             int M, int N, int K)
{
    __shared__ __align__(16) short As[128 * 32];
    __shared__ __align__(16) short Bs[128 * 32];
    const int tid  = threadIdx.x;
    const int wave = tid >> 6;
    const int lane = tid & 63;
    const int quad = lane >> 4;
    const int l16  = lane & 15;
    const int wm = wave >> 1, wn = wave & 1;          // 2x2 waves, 64x64 each
    const size_t bm = (size_t)blockIdx.y * 128;
    const size_t bn = (size_t)blockIdx.x * 128;

    floatx4 acc[4][4];
    for (int i = 0; i < 4; i++)
        for (int j = 0; j < 4; j++)
            acc[i][j] = (floatx4){0.f, 0.f, 0.f, 0.f};

    const int c0 = wave * 2, c1 = wave * 2 + 1;
    const int rA0 = c0 * 16 + (lane >> 2);
    const int rA1 = c1 * 16 + (lane >> 2);
    const int colOff = (lane & 3) * 8;

    for (int k0 = 0; k0 < K; k0 += 32) {
        load_lds16(A  + (bm + rA0) * (size_t)K + k0 + colOff, &As[c0 * 512]);
        load_lds16(A  + (bm + rA1) * (size_t)K + k0 + colOff, &As[c1 * 512]);
        load_lds16(Bt + (bn + rA0) * (size_t)K + k0 + colOff, &Bs[c0 * 512]);
        load_lds16(Bt + (bn + rA1) * (size_t)K + k0 + colOff, &Bs[c1 * 512]);
        __syncthreads();
        shortx8 af[4], bf[4];
        for (int mi = 0; mi < 4; mi++)
            af[mi] = *(const shortx8*)&As[(wm * 64 + mi * 16 + l16) * 32 + quad * 8];
        for (int ni = 0; ni < 4; ni++)
            bf[ni] = *(const shortx8*)&Bs[(wn * 64 + ni * 16 + l16) * 32 + quad * 8];
        for (int mi = 0; mi < 4; mi++)
            for (int ni = 0; ni < 4; ni++)
                acc[mi][ni] = __builtin_amdgcn_mfma_f32_16x16x32_bf16(
                    af[mi], bf[ni], acc[mi][ni], 0, 0, 0);
        __syncthreads();
    }

    for (int mi = 0; mi < 4; mi++) {
        for (int ni = 0; ni < 4; ni++) {
            const size_t row0 = bm + wm * 64 + mi * 16 + quad * 4;
            const size_t col  = bn + wn * 64 + ni * 16 + l16;
            for (int r = 0; r < 4; r++) {
                float v = acc[mi][ni][r];
                const size_t idx = (row0 + r) * (size_t)N + col;
                if (EPI == 0) {
                    Cb[idx] = f2bf(v);
                } else if (EPI == 1) {
                    v += bias[col];
                    Cb[idx] = f2bf(v > 0.f ? v : 0.f);
                } else if (EPI == 2) {
                    Cf[idx] = resid[idx] + v;
                } else {
                    v += bias[col];
                    Cf[idx] = resid[idx] + v;
                }
            }
        }
    }
}

// =====================================================================
// V transpose: qkv v-part -> vt[b][h][64 d][2048 s] bf16
// =====================================================================
__global__ __launch_bounds__(256)
void transpose_v(const short* __restrict__ qkv, short* __restrict__ vt)
{
    __shared__ __align__(16) short tile[64][65];
    const int st = blockIdx.x, h = blockIdx.y, b = blockIdx.z;
    const int t = threadIdx.x;
    for (int i = 0; i < 2; i++) {
        const int idx = i * 256 + t;
        const int s = idx >> 3, dg = idx & 7;
        shortx8 val = *(const shortx8*)&qkv[(size_t)(b * 2048 + st * 64 + s) * 3072
                                           + 2048 + h * 64 + dg * 8];
        for (int u = 0; u < 8; u++) tile[s][dg * 8 + u] = val[u];
    }
    __syncthreads();
    const int d = t >> 2, sg = (t & 3) * 16;
    shortx8 lo, hi;
    for (int i = 0; i < 8; i++) {
        lo[i] = tile[sg + i][d];
        hi[i] = tile[sg + 8 + i][d];
    }
    const size_t base = ((size_t)(b * 16 + h) * 64 + d) * 2048 + st * 64 + sg;
    *(shortx8*)&vt[base]     = lo;
    *(shortx8*)&vt[base + 8] = hi;
}

// =====================================================================
// Flash attention v5: v2 structure at max residency.
// 1 WG = 512 threads = 8 waves, 128 q-rows (16/wave). Grid 1024 WGs.
// K/V staged coalesced into LDS once per 128 q-rows (half of v2 traffic).
// LDS 36.9 KB -> 4 WG/CU -> 32 waves/CU fully co-resident.
//  - no running max; S^T = K.Q^T; l via constant-ones register MFMA
//  - P^T wave-private in LDS (lgkmcnt drain only, no 3rd barrier)
// qkv: [8192][3072] bf16 (q|k|v). vt: [b][h][64][2048] bf16. ctx: [8192][1024] bf16.
// =====================================================================
__global__ __launch_bounds__(512)
void attention_kernel(const short* __restrict__ qkv, const short* __restrict__ vt,
                      short* __restrict__ ctx)
{
    const int qt = blockIdx.x, h = blockIdx.y, b = blockIdx.z;
    const int tid  = threadIdx.x;
    const int wave = tid >> 6;          // 0..7
    const int lane = tid & 63;
    const int quad = lane >> 4;
    const int l16  = lane & 15;

    __shared__ __align__(16) short Ks[64 * 72];       // [s_local][d]
    __shared__ __align__(16) short Vs[64 * 72];       // [d][s_local]
    __shared__ __align__(16) short Ps[8][16 * 72];    // per-wave P^T [q_local][k]

    // Q fragment: B-operand, q-row = l16; pre-scaled by (1/8)*log2(e)
    const int q0 = qt * 128 + wave * 16;
    const float qscale = 0.125f * 1.44269504088896f;
    const short* qrow = qkv + (size_t)(b * 2048 + q0 + l16) * 3072 + h * 64;
    shortx8 qf[2];
    for (int kk = 0; kk < 2; kk++) {
        shortx8 raw = *(const shortx8*)&qrow[kk * 32 + quad * 8];
        for (int j = 0; j < 8; j++) raw[j] = f2bf(bf2f(raw[j]) * qscale);
        qf[kk] = raw;
    }

    // constant-ones B-operand fragment for the l row-sum MFMA
    shortx8 vones;
    for (int j = 0; j < 8; j++) vones[j] = (short)0x3F80;

    floatx4 accO[5];   // dt 0..3 = O columns; dt 4 = row-sum l
    for (int dt = 0; dt < 5; dt++) accO[dt] = (floatx4){0.f, 0.f, 0.f, 0.f};

    const short* kbase = qkv + (size_t)(b * 2048) * 3072 + 1024 + h * 64;
    const short* vbase = vt + ((size_t)(b * 16 + h) * 64) * 2048;
    short* const psw = &Ps[wave][0];

    // staging indices: 512 threads cover one 64x64 tile in a single pass
    const int ss = tid >> 3, sdg = tid & 7;

    for (int kt = 0; kt < 32; ++kt) {
        __syncthreads();   // previous tile fully consumed
        {
            shortx8 kv = *(const shortx8*)&kbase[(size_t)(kt * 64 + ss) * 3072 + sdg * 8];
            *(shortx8*)&Ks[ss * 72 + sdg * 8] = kv;
            shortx8 vv = *(const shortx8*)&vbase[(size_t)ss * 2048 + kt * 64 + sdg * 8];
            *(shortx8*)&Vs[ss * 72 + sdg * 8] = vv;
        }
        __syncthreads();

        // S^T = K.Q^T : rows = k-seq, cols = q (l16)
        floatx4 st[4];
        for (int nt = 0; nt < 4; nt++) {
            shortx8 kf0 = *(const shortx8*)&Ks[(nt * 16 + l16) * 72 + 0 * 32 + quad * 8];
            shortx8 kf1 = *(const shortx8*)&Ks[(nt * 16 + l16) * 72 + 1 * 32 + quad * 8];
            floatx4 c = (floatx4){0.f, 0.f, 0.f, 0.f};
            c = __builtin_amdgcn_mfma_f32_16x16x32_bf16(kf0, qf[0], c, 0, 0, 0);
            c = __builtin_amdgcn_mfma_f32_16x16x32_bf16(kf1, qf[1], c, 0, 0, 0);
            st[nt] = c;
        }

        // p = 2^s, pack 4 bf16, store P^T[q_local=l16][k] (wave-private)
        for (int nt = 0; nt < 4; nt++) {
            float2 p01, p23;
            p01.x = fast_exp2(st[nt][0]);
            p01.y = fast_exp2(st[nt][1]);
            p23.x = fast_exp2(st[nt][2]);
            p23.y = fast_exp2(st[nt][3]);
            union { __hip_bfloat162 h2[2]; uint2 u; } pk;
            pk.h2[0] = __float22bfloat162_rn(p01);
            pk.h2[1] = __float22bfloat162_rn(p23);
            *(uint2*)&psw[l16 * 72 + nt * 16 + quad * 4] = pk.u;
        }
        asm volatile("s_waitcnt lgkmcnt(0)" ::: "memory");

        shortx8 pf0 = *(const shortx8*)&psw[l16 * 72 + 0 * 32 + quad * 8];
        shortx8 pf1 = *(const shortx8*)&psw[l16 * 72 + 1 * 32 + quad * 8];

        // O[q][d] += P.V ; l via ones register
        for (int dt = 0; dt < 4; dt++) {
            shortx8 vf0 = *(const shortx8*)&Vs[(dt * 16 + l16) * 72 + 0 * 32 + quad * 8];
            shortx8 vf1 = *(const shortx8*)&Vs[(dt * 16 + l16) * 72 + 1 * 32 + quad * 8];
            floatx4 c = accO[dt];
            c = __builtin_amdgcn_mfma_f32_16x16x32_bf16(pf0, vf0, c, 0, 0, 0);
            c = __builtin_amdgcn_mfma_f32_16x16x32_bf16(pf1, vf1, c, 0, 0, 0);
            accO[dt] = c;
        }
        {
            floatx4 c = accO[4];
            c = __builtin_amdgcn_mfma_f32_16x16x32_bf16(pf0, vones, c, 0, 0, 0);
            c = __builtin_amdgcn_mfma_f32_16x16x32_bf16(pf1, vones, c, 0, 0, 0);
            accO[4] = c;
        }
    }

    // epilogue: ctx = O / l   (l identical across l16 in accO[4])
    const int qg = q0 + quad * 4;
    for (int r = 0; r < 4; r++) {
        const float inv = 1.0f / accO[4][r];
        for (int dt = 0; dt < 4; dt++)
            ctx[(size_t)(b * 2048 + qg + r) * 1024 + h * 64 + dt * 16 + l16]
                = f2bf(accO[dt][r] * inv);
    }
}

// =====================================================================
// launch
// =====================================================================
extern "C" void kernel_launch(void* const* d_in, const int* in_sizes, int n_in,
                              void* d_out, int out_size, void* d_ws, size_t ws_size,
                              hipStream_t stream)
{
    const float* x   = (const float*)d_in[0];
    const float* Wq  = (const float*)d_in[1];
    const float* Wk  = (const float*)d_in[2];
    const float* Wv  = (const float*)d_in[3];
    const float* Wo  = (const float*)d_in[4];
    const float* W1  = (const float*)d_in[5];
    const float* b1  = (const float*)d_in[6];
    const float* W2  = (const float*)d_in[7];
    const float* b2  = (const float*)d_in[8];
    const float* g1  = (const float*)d_in[9];
    const float* be1 = (const float*)d_in[10];
    const float* g2  = (const float*)d_in[11];
    const float* be2 = (const float*)d_in[12];
    float* out = (float*)d_out;
    char*  ws  = (char*)d_ws;

    const size_t MiB = 1u << 20;
    short* regA   = (short*)(ws);                 // 16 MiB: ln1 -> ctx -> ln2
    short* qkv    = (short*)(ws + 16 * MiB);      // 48 MiB
    short* vt     = (short*)(ws + 64 * MiB);      // 16 MiB
    short* ff1    = qkv;                          // 64 MiB alias (qkv+vt dead)
    short* Wqkv_t = (short*)(ws + 80 * MiB);      // 6 MiB
    short* Wo_t   = (short*)(ws + 86 * MiB);      // 2 MiB
    short* W1_t   = (short*)(ws + 88 * MiB);      // 8 MiB
    short* W2_t   = (short*)(ws + 96 * MiB);      // 8 MiB  (total 104 MiB)

    const dim3 blk(256);

    // weights -> bf16 BT layout
    transpose_w<<<dim3(32, 32),  blk, 0, stream>>>(Wq, Wqkv_t,                  1024, 1024);
    transpose_w<<<dim3(32, 32),  blk, 0, stream>>>(Wk, Wqkv_t + 1024 * 1024,    1024, 1024);
    transpose_w<<<dim3(32, 32),  blk, 0, stream>>>(Wv, Wqkv_t + 2 * 1024 * 1024,1024, 1024);
    transpose_w<<<dim3(32, 32),  blk, 0, stream>>>(Wo, Wo_t,                    1024, 1024);
    transpose_w<<<dim3(128, 32), blk, 0, stream>>>(W1, W1_t,                    1024, 4096);
    transpose_w<<<dim3(32, 128), blk, 0, stream>>>(W2, W2_t,                    4096, 1024);

    // LN1
    ln_bf16<<<8192, blk, 0, stream>>>(x, g1, be1, regA);
    // QKV
    gemm_bt<0><<<dim3(24, 64), blk, 0, stream>>>(regA, Wqkv_t, qkv, nullptr, nullptr, nullptr,
                                                 8192, 3072, 1024);
    // V^T
    transpose_v<<<dim3(32, 16, 4), blk, 0, stream>>>(qkv, vt);
    // attention -> ctx (regA)
    attention_kernel<<<dim3(16, 16, 4), dim3(512), 0, stream>>>(qkv, vt, regA);
    // attn_out @ Wo + x -> out (fp32)
    gemm_bt<2><<<dim3(8, 64), blk, 0, stream>>>(regA, Wo_t, nullptr, out, nullptr, x,
                                                8192, 1024, 1024);
    // LN2 -> regA
    ln_bf16<<<8192, blk, 0, stream>>>(out, g2, be2, regA);
    // FF1: relu(ln2 @ W1 + b1) -> ff1 (bf16)
    gemm_bt<1><<<dim3(32, 64), blk, 0, stream>>>(regA, W1_t, ff1, nullptr, b1, nullptr,
                                                 8192, 4096, 1024);
    // FF2: out += ff1 @ W2 + b2
    gemm_bt<3><<<dim3(8, 64), blk, 0, stream>>>(ff1, W2_t, nullptr, out, b2, out,
                                                8192, 1024, 4096);
}

// Round 6
// 572.575 us; speedup vs baseline: 1.3055x; 1.0230x over previous
//
#include <hip/hip_runtime.h>
#include <hip/hip_bf16.h>

typedef __attribute__((ext_vector_type(4)))  float  floatx4;
typedef __attribute__((ext_vector_type(16))) float  floatx16;
typedef __attribute__((ext_vector_type(8)))  short  shortx8;
typedef __attribute__((ext_vector_type(4)))  short  shortx4;

// ---------- bf16 helpers (bit-level, RNE) ----------
__device__ __forceinline__ short f2bf(float f) {
    unsigned u = __float_as_uint(f);
    u += 0x7fffu + ((u >> 16) & 1u);
    return (short)(u >> 16);
}
__device__ __forceinline__ float bf2f(short s) {
    return __uint_as_float(((unsigned)(unsigned short)s) << 16);
}
__device__ __forceinline__ float fast_exp2(float x) {
#if __has_builtin(__builtin_amdgcn_exp2f)
    return __builtin_amdgcn_exp2f(x);
#else
    return exp2f(x);
#endif
}

// ---------- async global->LDS, 16B per lane ----------
__device__ __forceinline__ void load_lds16(const void* g, void* l) {
    __builtin_amdgcn_global_load_lds(
        (const __attribute__((address_space(1))) unsigned int*)g,
        (__attribute__((address_space(3))) unsigned int*)l,
        16, 0, 0);
}

// =====================================================================
// Weight transpose+convert: src fp32 [K][N] -> dst bf16 [N][K]
// =====================================================================
__global__ __launch_bounds__(256)
void transpose_w(const float* __restrict__ src, short* __restrict__ dst, int K, int N)
{
    __shared__ __align__(16) float tile[32][33];
    const int n0 = blockIdx.x * 32, k0 = blockIdx.y * 32;
    const int tx = threadIdx.x & 31, ty = threadIdx.x >> 5;   // ty 0..7
    for (int i = 0; i < 32; i += 8)
        tile[ty + i][tx] = src[(size_t)(k0 + ty + i) * N + n0 + tx];
    __syncthreads();
    for (int i = 0; i < 32; i += 8)
        dst[(size_t)(n0 + ty + i) * K + k0 + tx] = f2bf(tile[tx][ty + i]);
}

// =====================================================================
// LayerNorm fp32 [8192][1024] -> bf16, 1 block/row
// =====================================================================
__global__ __launch_bounds__(256)
void ln_bf16(const float* __restrict__ x, const float* __restrict__ g,
             const float* __restrict__ be, short* __restrict__ out)
{
    const int row = blockIdx.x;
    const int tid = threadIdx.x;
    const float4 v = reinterpret_cast<const float4*>(x + (size_t)row * 1024)[tid];
    float s  = v.x + v.y + v.z + v.w;
    float ss = v.x * v.x + v.y * v.y + v.z * v.z + v.w * v.w;
    for (int off = 32; off > 0; off >>= 1) {
        s  += __shfl_down(s,  off);
        ss += __shfl_down(ss, off);
    }
    __shared__ float rs[4], rss[4];
    const int wave = tid >> 6, lane = tid & 63;
    if (lane == 0) { rs[wave] = s; rss[wave] = ss; }
    __syncthreads();
    const float S    = rs[0] + rs[1] + rs[2] + rs[3];
    const float SS   = rss[0] + rss[1] + rss[2] + rss[3];
    const float mean = S * (1.0f / 1024.0f);
    const float var  = SS * (1.0f / 1024.0f) - mean * mean;
    const float rstd = rsqrtf(var + 1e-5f);
    const float4 gg = reinterpret_cast<const float4*>(g)[tid];
    const float4 bb = reinterpret_cast<const float4*>(be)[tid];
    shortx4 o;
    o[0] = f2bf(gg.x * ((v.x - mean) * rstd) + bb.x);
    o[1] = f2bf(gg.y * ((v.y - mean) * rstd) + bb.y);
    o[2] = f2bf(gg.z * ((v.z - mean) * rstd) + bb.z);
    o[3] = f2bf(gg.w * ((v.w - mean) * rstd) + bb.w);
    *reinterpret_cast<shortx4*>(out + (size_t)row * 1024 + tid * 4) = o;
}

// =====================================================================
// m97-style bf16 GEMM: C[M][N] = A[M][K] @ Bt[N][K]^T, fused epilogues.
// EPI 0: store bf16
// EPI 1: +bias, relu, store bf16
// EPI 2: fp32 out = resid + acc
// EPI 3: fp32 out = resid + acc + bias
// =====================================================================
template <int EPI>
__global__ __launch_bounds__(256)
void gemm_bt(const short* __restrict__ A, const short* __restrict__ Bt,
             short* __restrict__ Cb, float* __restrict__ Cf,
             const float* __restrict__ bias, const float* __restrict__ resid,
             int M, int N, int K)
{
    __shared__ __align__(16) short As[128 * 32];
    __shared__ __align__(16) short Bs[128 * 32];
    const int tid  = threadIdx.x;
    const int wave = tid >> 6;
    const int lane = tid & 63;
    const int quad = lane >> 4;
    const int l16  = lane & 15;
    const int wm = wave >> 1, wn = wave & 1;          // 2x2 waves, 64x64 each
    const size_t bm = (size_t)blockIdx.y * 128;
    const size_t bn = (size_t)blockIdx.x * 128;

    floatx4 acc[4][4];
    for (int i = 0; i < 4; i++)
        for (int j = 0; j < 4; j++)
            acc[i][j] = (floatx4){0.f, 0.f, 0.f, 0.f};

    const int c0 = wave * 2, c1 = wave * 2 + 1;
    const int rA0 = c0 * 16 + (lane >> 2);
    const int rA1 = c1 * 16 + (lane >> 2);
    const int colOff = (lane & 3) * 8;

    for (int k0 = 0; k0 < K; k0 += 32) {
        load_lds16(A  + (bm + rA0) * (size_t)K + k0 + colOff, &As[c0 * 512]);
        load_lds16(A  + (bm + rA1) * (size_t)K + k0 + colOff, &As[c1 * 512]);
        load_lds16(Bt + (bn + rA0) * (size_t)K + k0 + colOff, &Bs[c0 * 512]);
        load_lds16(Bt + (bn + rA1) * (size_t)K + k0 + colOff, &Bs[c1 * 512]);
        __syncthreads();
        shortx8 af[4], bf[4];
        for (int mi = 0; mi < 4; mi++)
            af[mi] = *(const shortx8*)&As[(wm * 64 + mi * 16 + l16) * 32 + quad * 8];
        for (int ni = 0; ni < 4; ni++)
            bf[ni] = *(const shortx8*)&Bs[(wn * 64 + ni * 16 + l16) * 32 + quad * 8];
        for (int mi = 0; mi < 4; mi++)
            for (int ni = 0; ni < 4; ni++)
                acc[mi][ni] = __builtin_amdgcn_mfma_f32_16x16x32_bf16(
                    af[mi], bf[ni], acc[mi][ni], 0, 0, 0);
        __syncthreads();
    }

    for (int mi = 0; mi < 4; mi++) {
        for (int ni = 0; ni < 4; ni++) {
            const size_t row0 = bm + wm * 64 + mi * 16 + quad * 4;
            const size_t col  = bn + wn * 64 + ni * 16 + l16;
            for (int r = 0; r < 4; r++) {
                float v = acc[mi][ni][r];
                const size_t idx = (row0 + r) * (size_t)N + col;
                if (EPI == 0) {
                    Cb[idx] = f2bf(v);
                } else if (EPI == 1) {
                    v += bias[col];
                    Cb[idx] = f2bf(v > 0.f ? v : 0.f);
                } else if (EPI == 2) {
                    Cf[idx] = resid[idx] + v;
                } else {
                    v += bias[col];
                    Cf[idx] = resid[idx] + v;
                }
            }
        }
    }
}

// =====================================================================
// V transpose: qkv v-part -> vt[b][h][64 d][2048 s] bf16
// =====================================================================
__global__ __launch_bounds__(256)
void transpose_v(const short* __restrict__ qkv, short* __restrict__ vt)
{
    __shared__ __align__(16) short tile[64][65];
    const int st = blockIdx.x, h = blockIdx.y, b = blockIdx.z;
    const int t = threadIdx.x;
    for (int i = 0; i < 2; i++) {
        const int idx = i * 256 + t;
        const int s = idx >> 3, dg = idx & 7;
        shortx8 val = *(const shortx8*)&qkv[(size_t)(b * 2048 + st * 64 + s) * 3072
                                           + 2048 + h * 64 + dg * 8];
        for (int u = 0; u < 8; u++) tile[s][dg * 8 + u] = val[u];
    }
    __syncthreads();
    const int d = t >> 2, sg = (t & 3) * 16;
    shortx8 lo, hi;
    for (int i = 0; i < 8; i++) {
        lo[i] = tile[sg + i][d];
        hi[i] = tile[sg + 8 + i][d];
    }
    const size_t base = ((size_t)(b * 16 + h) * 64 + d) * 2048 + st * 64 + sg;
    *(shortx8*)&vt[base]     = lo;
    *(shortx8*)&vt[base + 8] = hi;
}

// =====================================================================
// Flash attention v6: 32x32x16 MFMA, 2x arithmetic intensity per LDS byte.
// 1 WG = 512 threads = 8 waves; each wave owns 32 q-rows (WG = 256 q-rows).
// Grid (8, 16, 4) = 512 WGs. LDS 54KB -> 2 WG/CU -> 16 waves/CU.
//  - S^T[kseq][q] via A=K(LDS), B=Q(reg): C col = q = lane&31
//  - l = per-lane VALU sum of own p's (+1 shfl_xor at end) - no ones-MFMA
//  - P^T round-trip: wave-private [q][s] tile, b64 writes / b128 reads
//  - O^T[d][q] via A=V^T(LDS), B=P^T(LDS): epilogue divide is lane-local
// qkv: [8192][3072] bf16 (q|k|v). vt: [b][h][64][2048] bf16. ctx: [8192][1024] bf16.
// =====================================================================
__global__ __launch_bounds__(512, 4)
void attention_kernel(const short* __restrict__ qkv, const short* __restrict__ vt,
                      short* __restrict__ ctx)
{
    const int qt = blockIdx.x, h = blockIdx.y, b = blockIdx.z;
    const int tid  = threadIdx.x;
    const int wave = tid >> 6;          // 0..7
    const int lane = tid & 63;
    const int l32  = lane & 31;
    const int hf   = lane >> 5;         // 0/1

    __shared__ __align__(16) short Ks[64 * 72];        // [kseq][d], stride 72
    __shared__ __align__(16) short Vs[64 * 72];        // [d][s],   stride 72
    __shared__ __align__(16) short Ps[8][32 * 72];     // per-wave P [q][s], stride 72

    // Q fragments (B-operand): n = q = l32, k = d = dk*16 + hf*8 + j
    const int q0 = qt * 256 + wave * 32;
    const float qscale = 0.125f * 1.44269504088896f;
    const short* qrow = qkv + (size_t)(b * 2048 + q0 + l32) * 3072 + h * 64;
    shortx8 qf[4];
    for (int dk = 0; dk < 4; dk++) {
        shortx8 raw = *(const shortx8*)&qrow[dk * 16 + hf * 8];
        for (int j = 0; j < 8; j++) raw[j] = f2bf(bf2f(raw[j]) * qscale);
        qf[dk] = raw;
    }

    floatx16 accO[2];                   // O^T: col=q=l32, rows d=(reg&3)+8*(reg>>2)+4*hf (+32t)
    for (int t = 0; t < 2; t++)
        for (int r = 0; r < 16; r++) accO[t][r] = 0.f;
    float lsum = 0.f;

    const short* kbase = qkv + (size_t)(b * 2048) * 3072 + 1024 + h * 64;
    const short* vbase = vt + ((size_t)(b * 16 + h) * 64) * 2048;
    short* const psw = &Ps[wave][0];
    unsigned* const pswd = (unsigned*)psw;

    // staging: 512 threads cover one 64x64 tile per array in a single pass
    const int ss = tid >> 3, sdg = tid & 7;

    for (int kt = 0; kt < 32; ++kt) {
        __syncthreads();   // previous tile fully consumed
        {
            shortx8 kv = *(const shortx8*)&kbase[(size_t)(kt * 64 + ss) * 3072 + sdg * 8];
            *(shortx8*)&Ks[ss * 72 + sdg * 8] = kv;
            shortx8 vv = *(const shortx8*)&vbase[(size_t)ss * 2048 + kt * 64 + sdg * 8];
            *(shortx8*)&Vs[ss * 72 + sdg * 8] = vv;
        }
        __syncthreads();

        // S^T = K.Q^T, two 32x32 kseq-tiles; exp2 + lane-local l + P store
        for (int t = 0; t < 2; t++) {
            floatx16 c;
            for (int r = 0; r < 16; r++) c[r] = 0.f;
            for (int dk = 0; dk < 4; dk++) {
                shortx8 kf = *(const shortx8*)&Ks[(t * 32 + l32) * 72 + dk * 16 + hf * 8];
                c = __builtin_amdgcn_mfma_f32_32x32x16_bf16(kf, qf[dk], c, 0, 0, 0);
            }
            // rows s = (reg&3) + 8*(reg>>2) + 4*hf (+32t), col q = l32 (this lane)
            for (int R = 0; R < 4; R++) {
                float2 a, bb;
                a.x  = fast_exp2(c[4 * R + 0]);
                a.y  = fast_exp2(c[4 * R + 1]);
                bb.x = fast_exp2(c[4 * R + 2]);
                bb.y = fast_exp2(c[4 * R + 3]);
                lsum += (a.x + a.y) + (bb.x + bb.y);
                union { __hip_bfloat162 h2[2]; uint2 u; } pk;
                pk.h2[0] = __float22bfloat162_rn(a);
                pk.h2[1] = __float22bfloat162_rn(bb);
                // dword index within row q: (t*32 + 8R + 4hf)/2 = t*16 + 4R + 2hf
                *(uint2*)&pswd[l32 * 36 + t * 16 + 4 * R + 2 * hf] = pk.u;
            }
        }
        asm volatile("s_waitcnt lgkmcnt(0)" ::: "memory");   // wave-private P ready

        // P^T B-fragments: n = q = l32, k = s = sk*16 + hf*8 + j
        shortx8 pf[4];
        for (int sk = 0; sk < 4; sk++)
            pf[sk] = *(const shortx8*)&psw[l32 * 72 + sk * 16 + hf * 8];

        // O^T += V^T.P^T : A = Vs rows d, two 32-d tiles
        for (int t = 0; t < 2; t++) {
            floatx16 c = accO[t];
            for (int sk = 0; sk < 4; sk++) {
                shortx8 vf = *(const shortx8*)&Vs[(t * 32 + l32) * 72 + sk * 16 + hf * 8];
                c = __builtin_amdgcn_mfma_f32_32x32x16_bf16(vf, pf[sk], c, 0, 0, 0);
            }
            accO[t] = c;
        }
    }

    // epilogue: l = own + partner(lane^32); divide; pack; store
    const float lfull = lsum + __shfl_xor(lsum, 32);
    const float inv = 1.0f / lfull;
    const size_t crow = (size_t)(b * 2048 + q0 + l32) * 1024 + h * 64;
    for (int t = 0; t < 2; t++)
        for (int R = 0; R < 4; R++) {
            float2 a, bb;
            a.x  = accO[t][4 * R + 0] * inv;
            a.y  = accO[t][4 * R + 1] * inv;
            bb.x = accO[t][4 * R + 2] * inv;
            bb.y = accO[t][4 * R + 3] * inv;
            union { __hip_bfloat162 h2[2]; uint2 u; } pk;
            pk.h2[0] = __float22bfloat162_rn(a);
            pk.h2[1] = __float22bfloat162_rn(bb);
            *(uint2*)&ctx[crow + t * 32 + 8 * R + 4 * hf] = pk.u;
        }
}

// =====================================================================
// launch
// =====================================================================
extern "C" void kernel_launch(void* const* d_in, const int* in_sizes, int n_in,
                              void* d_out, int out_size, void* d_ws, size_t ws_size,
                              hipStream_t stream)
{
    const float* x   = (const float*)d_in[0];
    const float* Wq  = (const float*)d_in[1];
    const float* Wk  = (const float*)d_in[2];
    const float* Wv  = (const float*)d_in[3];
    const float* Wo  = (const float*)d_in[4];
    const float* W1  = (const float*)d_in[5];
    const float* b1  = (const float*)d_in[6];
    const float* W2  = (const float*)d_in[7];
    const float* b2  = (const float*)d_in[8];
    const float* g1  = (const float*)d_in[9];
    const float* be1 = (const float*)d_in[10];
    const float* g2  = (const float*)d_in[11];
    const float* be2 = (const float*)d_in[12];
    float* out = (float*)d_out;
    char*  ws  = (char*)d_ws;

    const size_t MiB = 1u << 20;
    short* regA   = (short*)(ws);                 // 16 MiB: ln1 -> ctx -> ln2
    short* qkv    = (short*)(ws + 16 * MiB);      // 48 MiB
    short* vt     = (short*)(ws + 64 * MiB);      // 16 MiB
    short* ff1    = qkv;                          // 64 MiB alias (qkv+vt dead)
    short* Wqkv_t = (short*)(ws + 80 * MiB);      // 6 MiB
    short* Wo_t   = (short*)(ws + 86 * MiB);      // 2 MiB
    short* W1_t   = (short*)(ws + 88 * MiB);      // 8 MiB
    short* W2_t   = (short*)(ws + 96 * MiB);      // 8 MiB  (total 104 MiB)

    const dim3 blk(256);

    // weights -> bf16 BT layout
    transpose_w<<<dim3(32, 32),  blk, 0, stream>>>(Wq, Wqkv_t,                  1024, 1024);
    transpose_w<<<dim3(32, 32),  blk, 0, stream>>>(Wk, Wqkv_t + 1024 * 1024,    1024, 1024);
    transpose_w<<<dim3(32, 32),  blk, 0, stream>>>(Wv, Wqkv_t + 2 * 1024 * 1024,1024, 1024);
    transpose_w<<<dim3(32, 32),  blk, 0, stream>>>(Wo, Wo_t,                    1024, 1024);
    transpose_w<<<dim3(128, 32), blk, 0, stream>>>(W1, W1_t,                    1024, 4096);
    transpose_w<<<dim3(32, 128), blk, 0, stream>>>(W2, W2_t,                    4096, 1024);

    // LN1
    ln_bf16<<<8192, blk, 0, stream>>>(x, g1, be1, regA);
    // QKV
    gemm_bt<0><<<dim3(24, 64), blk, 0, stream>>>(regA, Wqkv_t, qkv, nullptr, nullptr, nullptr,
                                                 8192, 3072, 1024);
    // V^T
    transpose_v<<<dim3(32, 16, 4), blk, 0, stream>>>(qkv, vt);
    // attention -> ctx (regA)
    attention_kernel<<<dim3(8, 16, 4), dim3(512), 0, stream>>>(qkv, vt, regA);
    // attn_out @ Wo + x -> out (fp32)
    gemm_bt<2><<<dim3(8, 64), blk, 0, stream>>>(regA, Wo_t, nullptr, out, nullptr, x,
                                                8192, 1024, 1024);
    // LN2 -> regA
    ln_bf16<<<8192, blk, 0, stream>>>(out, g2, be2, regA);
    // FF1: relu(ln2 @ W1 + b1) -> ff1 (bf16)
    gemm_bt<1><<<dim3(32, 64), blk, 0, stream>>>(regA, W1_t, ff1, nullptr, b1, nullptr,
                                                 8192, 4096, 1024);
    // FF2: out += ff1 @ W2 + b2
    gemm_bt<3><<<dim3(8, 64), blk, 0, stream>>>(ff1, W2_t, nullptr, out, b2, out,
                                                8192, 1024, 4096);
}